// Round 10
// baseline (596.816 us; speedup 1.0000x reference)
//
#include <hip/hip_runtime.h>
#include <hip/hip_bf16.h>
#include <hip/hip_cooperative_groups.h>
#include <math.h>

namespace cg = cooperative_groups;

// Problem constants
#define Bb 8
#define Tt 1024
#define Jj 25
#define D_MODEL 256
#define D_STATE 16
#define D_CONV 4
#define D_INNER 512
#define DT_RANK 16
#define N_CLASSES 60
#define Mrows (Bb*Tt)   // 8192
#define NC 64           // scan chunks
#define CL 16           // chunk length (NC*CL == Tt)

typedef unsigned short u16;
using bf16x8 = __attribute__((ext_vector_type(8))) __bf16;
using f32x4  = __attribute__((ext_vector_type(4))) float;

// ---- bf16 split helpers ----------------------------------------------------
__device__ inline u16 f2bf(float x) {
    unsigned u = __float_as_uint(x);
    unsigned r = (u + 0x7fffu + ((u >> 16) & 1u)) >> 16;
    return (u16)r;
}
__device__ inline float bf2f(u16 h) { return __uint_as_float((unsigned)h << 16); }
__device__ inline void split2(float x, u16& h, u16& l) {
    h = f2bf(x);
    l = f2bf(x - bf2f(h));
}
__device__ inline float softplus_fast(float s) {
    return fmaxf(s, 0.f) + __logf(1.f + __expf(-fabsf(s)));
}
__device__ inline f32x4 mfma3(bf16x8 ah, bf16x8 al, bf16x8 bh, bf16x8 bl, f32x4 c) {
    c = __builtin_amdgcn_mfma_f32_16x16x32_bf16(al, bh, c, 0, 0, 0);
    c = __builtin_amdgcn_mfma_f32_16x16x32_bf16(ah, bl, c, 0, 0, 0);
    c = __builtin_amdgcn_mfma_f32_16x16x32_bf16(ah, bh, c, 0, 0, 0);
    return c;
}

// ---------------------------------------------------------------------------
// prep: blocks 0..8191 featurize; 8192..10079 weight cvt; 10080..10207 zero bp
// ---------------------------------------------------------------------------
__global__ __launch_bounds__(256) void prep_kernel(
    const float* __restrict__ x, u16* __restrict__ fh, u16* __restrict__ fl,
    const float* __restrict__ ew, const float* __restrict__ iw,
    const float* __restrict__ xw, const float* __restrict__ ow,
    u16* __restrict__ ebh, u16* __restrict__ ebl,
    u16* __restrict__ iph, u16* __restrict__ ipl,
    u16* __restrict__ xph, u16* __restrict__ xpl,
    u16* __restrict__ oph, u16* __restrict__ opl,
    float* __restrict__ blockpart) {
    int blk = blockIdx.x;
    if (blk < Mrows) {
        int r = blk;
        int c = threadIdx.x;
        float v = 0.f;
        if (c < 225) {
            int t = r & (Tt - 1);
            int j = c / 9;
            int cc = c - j * 9;
            int comp = cc % 3;
            int kind = cc / 3;
            auto POS = [&](int dt) -> float {
                const float* p = x + (long)(r - dt) * Jj * 3;
                return p[j * 3 + comp] - p[comp];
            };
            if (kind == 0) v = POS(0);
            else if (kind == 1) v = (t >= 1) ? (POS(0) - POS(1)) : 0.f;
            else {
                if (t >= 2)      v = POS(0) - 2.f * POS(1) + POS(2);
                else if (t == 1) v = POS(0) - POS(1);
                else             v = 0.f;
            }
        }
        u16 h, l;
        split2(v, h, l);
        fh[(long)r * 256 + c] = h;
        fl[(long)r * 256 + c] = l;
    } else if (blk < Mrows + 1888) {
        int i = (blk - Mrows) * 256 + threadIdx.x;   // 0..483327
        const float* src; u16 *dh, *dl; int K, kshift, idx;
        if (i < 65536)       { src = ew; dh = ebh; dl = ebl; K = 225; kshift = 8; idx = i; }
        else if (i < 327680) { src = iw; dh = iph; dl = ipl; K = 256; kshift = 8; idx = i - 65536; }
        else if (i < 352256) { src = xw; dh = xph; dl = xpl; K = 512; kshift = 9; idx = i - 327680; }
        else                 { src = ow; dh = oph; dl = opl; K = 512; kshift = 9; idx = i - 352256; }
        int n = idx >> kshift;
        int k = idx & ((1 << kshift) - 1);
        float v = (k < K) ? src[(long)n * K + k] : 0.f;
        u16 h, l;
        split2(v, h, l);
        dh[idx] = h;
        dl[idx] = l;
    } else {
        // zero blockpart (128 blocks x 256)
        int i = (blk - Mrows - 1888) * 256 + threadIdx.x;
        blockpart[i] = 0.f;
    }
}

// ---------------------------------------------------------------------------
// bf16x3 MFMA GEMM with epilogue. EPI: 0=none, 1=+bias, 3=+resid
// ---------------------------------------------------------------------------
template<int BM, int BN, int EPI>
__global__ __launch_bounds__(256) void gemm_mfma(
    const u16* __restrict__ Ahi, const u16* __restrict__ Alo, int lda,
    const u16* __restrict__ Whi, const u16* __restrict__ Wlo, int ldw,
    const float* __restrict__ bias, const float* __restrict__ resid, int ldr,
    float* __restrict__ C, int ldc, int M, int N, int K)
{
    constexpr int TM = BM / 32;
    constexpr int TN = BN / 32;
    constexpr int SA = 40;
    __shared__ u16 AsH[BM * SA], AsL[BM * SA];
    __shared__ u16 WsH[BN * SA], WsL[BN * SA];
    int tid = threadIdx.x;
    int m0 = blockIdx.y * BM;
    int n0 = blockIdx.x * BN;
    int lane = tid & 63;
    int wave = tid >> 6;
    int wm = wave >> 1, wn = wave & 1;
    int fr = lane & 15, quad = lane >> 4;
    f32x4 acc[TM][TN] = {};

    for (int k0 = 0; k0 < K; k0 += 32) {
        for (int s = tid; s < BM * 4; s += 256) {
            int row = s >> 2, seg = s & 3;
            long off = (long)(m0 + row) * lda + k0 + seg * 8;
            *(uint4*)&AsH[row * SA + seg * 8] = *(const uint4*)(Ahi + off);
            *(uint4*)&AsL[row * SA + seg * 8] = *(const uint4*)(Alo + off);
        }
        for (int s = tid; s < BN * 4; s += 256) {
            int row = s >> 2, seg = s & 3;
            long off = (long)(n0 + row) * ldw + k0 + seg * 8;
            *(uint4*)&WsH[row * SA + seg * 8] = *(const uint4*)(Whi + off);
            *(uint4*)&WsL[row * SA + seg * 8] = *(const uint4*)(Wlo + off);
        }
        __syncthreads();
        bf16x8 aH[TM], aL[TM], bH[TN], bL[TN];
#pragma unroll
        for (int im = 0; im < TM; im++) {
            int r = wm * (BM / 2) + im * 16 + fr;
            aH[im] = *(const bf16x8*)&AsH[r * SA + quad * 8];
            aL[im] = *(const bf16x8*)&AsL[r * SA + quad * 8];
        }
#pragma unroll
        for (int in = 0; in < TN; in++) {
            int r = wn * (BN / 2) + in * 16 + fr;
            bH[in] = *(const bf16x8*)&WsH[r * SA + quad * 8];
            bL[in] = *(const bf16x8*)&WsL[r * SA + quad * 8];
        }
#pragma unroll
        for (int im = 0; im < TM; im++)
#pragma unroll
            for (int in = 0; in < TN; in++)
                acc[im][in] = mfma3(aH[im], aL[im], bH[in], bL[in], acc[im][in]);
        __syncthreads();
    }
#pragma unroll
    for (int im = 0; im < TM; im++) {
#pragma unroll
        for (int in = 0; in < TN; in++) {
#pragma unroll
            for (int reg = 0; reg < 4; reg++) {
                int gm = m0 + wm * (BM / 2) + im * 16 + quad * 4 + reg;
                int gn = n0 + wn * (BN / 2) + in * 16 + fr;
                float v = acc[im][in][reg];
                if (EPI == 1) v += bias[gn];
                if (EPI == 3) v += resid[(long)gm * ldr + gn];
                C[(long)gm * ldc + gn] = v;
            }
        }
    }
}

// ---------------------------------------------------------------------------
// LayerNorm over D=256 per row (8192 blocks) -> bf16 hi/lo.
// ---------------------------------------------------------------------------
__global__ __launch_bounds__(256) void ln_kernel(const float* __restrict__ x,
                                                 const float* __restrict__ g,
                                                 const float* __restrict__ b,
                                                 u16* outh, u16* outl) {
    __shared__ float red[256];
    long r = blockIdx.x;
    int d = threadIdx.x;
    float v = x[r * 256 + d];
    red[d] = v;
    __syncthreads();
    for (int s = 128; s > 0; s >>= 1) {
        if (d < s) red[d] += red[d + s];
        __syncthreads();
    }
    float mu = red[0] * (1.f / 256.f);
    __syncthreads();
    float dv = v - mu;
    red[d] = dv * dv;
    __syncthreads();
    for (int s = 128; s > 0; s >>= 1) {
        if (d < s) red[d] += red[d + s];
        __syncthreads();
    }
    float var = red[0] * (1.f / 256.f);
    float o = dv * rsqrtf(var + 1e-5f) * g[d] + b[d];
    u16 h, l;
    split2(o, h, l);
    outh[r * 256 + d] = h;
    outl[r * 256 + d] = l;
}

// ---------------------------------------------------------------------------
// Post-LN + pool partial: per-row LN, atomicAdd into blockpart[r/64][d].
// ---------------------------------------------------------------------------
__global__ __launch_bounds__(256) void ln_pool_kernel(const float* __restrict__ x,
                                                      const float* __restrict__ g,
                                                      const float* __restrict__ b,
                                                      float* __restrict__ bp) {
    __shared__ float red[256];
    long r = blockIdx.x;
    int d = threadIdx.x;
    float v = x[r * 256 + d];
    red[d] = v;
    __syncthreads();
    for (int s = 128; s > 0; s >>= 1) {
        if (d < s) red[d] += red[d + s];
        __syncthreads();
    }
    float mu = red[0] * (1.f / 256.f);
    __syncthreads();
    float dv = v - mu;
    red[d] = dv * dv;
    __syncthreads();
    for (int s = 128; s > 0; s >>= 1) {
        if (d < s) red[d] += red[d + s];
        __syncthreads();
    }
    float var = red[0] * (1.f / 256.f);
    float o = dv * rsqrtf(var + 1e-5f) * g[d] + b[d];
    atomicAdd(&bp[(r >> 6) * 256 + d], o);
}

// ---------------------------------------------------------------------------
// Fused conv+SiLU+x_proj. BM=16 rows/block, grid 512 -> 2 blocks/CU.
// ---------------------------------------------------------------------------
__global__ __launch_bounds__(256) void conv_xproj_kernel(
    const float* __restrict__ xz,
    const float* __restrict__ cw, const float* __restrict__ cb,
    const u16* __restrict__ Whi, const u16* __restrict__ Wlo,  // [48][512]
    u16* __restrict__ xmh, u16* __restrict__ xml,
    float* __restrict__ dbl)
{
    constexpr int SA = 40;
    __shared__ u16 AsH[16 * SA], AsL[16 * SA];
    __shared__ u16 WsH[64 * SA], WsL[64 * SA];
    int tid = threadIdx.x;
    int m0 = blockIdx.x * 16;
    int lane = tid & 63, wave = tid >> 6;
    int fr = lane & 15, quad = lane >> 4;
    f32x4 acc = {};

    if (tid < 64) {
        int wr = 48 + (tid >> 2), seg = tid & 3;
        *(uint4*)&WsH[wr * SA + seg * 8] = make_uint4(0, 0, 0, 0);
        *(uint4*)&WsL[wr * SA + seg * 8] = make_uint4(0, 0, 0, 0);
    }

    int row = tid >> 4;          // 0..15
    int cg  = tid & 15;          // 2 cols each
    long gr = m0 + row;
    int t = gr & (Tt - 1);
    const float* xzr = xz + gr * 1024;

    for (int k0 = 0; k0 < 512; k0 += 32) {
        int c0 = k0 + cg * 2;
        float2 x0 = *(const float2*)(xzr + c0);
        float2 x1 = (t >= 1) ? *(const float2*)(xzr - 1024 + c0) : make_float2(0, 0);
        float2 x2 = (t >= 2) ? *(const float2*)(xzr - 2048 + c0) : make_float2(0, 0);
        float2 x3 = (t >= 3) ? *(const float2*)(xzr - 3072 + c0) : make_float2(0, 0);
        u16 hh0, ll0, hh1, ll1;
        {
            float4 w = *(const float4*)(cw + (c0 + 0) * 4);
            float a = cb[c0 + 0] + w.w * x0.x + w.z * x1.x + w.y * x2.x + w.x * x3.x;
            float s = a / (1.f + __expf(-a));
            split2(s, hh0, ll0);
            w = *(const float4*)(cw + (c0 + 1) * 4);
            a = cb[c0 + 1] + w.w * x0.y + w.z * x1.y + w.y * x2.y + w.x * x3.y;
            s = a / (1.f + __expf(-a));
            split2(s, hh1, ll1);
        }
        unsigned ph = hh0 | ((unsigned)hh1 << 16);
        unsigned pl = ll0 | ((unsigned)ll1 << 16);
        *(unsigned*)(xmh + gr * 512 + c0) = ph;
        *(unsigned*)(xml + gr * 512 + c0) = pl;
        *(unsigned*)&AsH[row * SA + cg * 2] = ph;
        *(unsigned*)&AsL[row * SA + cg * 2] = pl;
        if (tid < 192) {
            int wr = tid >> 2, seg = tid & 3;
            long off = (long)wr * 512 + k0 + seg * 8;
            *(uint4*)&WsH[wr * SA + seg * 8] = *(const uint4*)(Whi + off);
            *(uint4*)&WsL[wr * SA + seg * 8] = *(const uint4*)(Wlo + off);
        }
        __syncthreads();
        bf16x8 aH = *(const bf16x8*)&AsH[fr * SA + quad * 8];
        bf16x8 aL = *(const bf16x8*)&AsL[fr * SA + quad * 8];
        int wrow = wave * 16 + fr;
        bf16x8 bH = *(const bf16x8*)&WsH[wrow * SA + quad * 8];
        bf16x8 bL = *(const bf16x8*)&WsL[wrow * SA + quad * 8];
        acc = mfma3(aH, aL, bH, bL, acc);
        __syncthreads();
    }
    int gn = wave * 16 + fr;
    if (gn < 48) {
#pragma unroll
        for (int reg = 0; reg < 4; reg++) {
            int gm = m0 + quad * 4 + reg;
            dbl[(long)gm * 48 + gn] = acc[reg];
        }
    }
}

// ---------------------------------------------------------------------------
// Fused cooperative scan: p1 + combine + p2 in one launch.
// Grid (8, 64) = 512 blocks x 512 threads = exactly 2 blocks/CU co-resident.
// LDS dbl slab + u[CL] registers persist across phases.
// ---------------------------------------------------------------------------
__global__ __launch_bounds__(512, 4) void scan_fused(
    const float* __restrict__ dbl,
    const float* __restrict__ dtw, const float* __restrict__ dtb,
    const u16* xmh, const u16* xml,
    const float* __restrict__ xz,
    const float* __restrict__ A_log, const float* __restrict__ Dv,
    float* chunkS, float* sumdelta,
    u16* yh, u16* yl)
{
    cg::grid_group grid = cg::this_grid();
    __shared__ float ds[CL * 48];
    int b = blockIdx.x, c = blockIdx.y, d = threadIdx.x;
    long r0 = (long)b * Tt + (long)c * CL;
    for (int i = d; i < CL * 48; i += 512) ds[i] = dbl[r0 * 48 + i];

    float Arow[16];
#pragma unroll
    for (int n = 0; n < 16; n++) Arow[n] = -expf(A_log[d * 16 + n]);
    float4 wd[4];
#pragma unroll
    for (int q = 0; q < 4; q++) wd[q] = *(const float4*)(dtw + d * 16 + q * 4);
    float bdt = dtb[d];
    float uu[CL];
    float S[16];
#pragma unroll
    for (int n = 0; n < 16; n++) S[n] = 0.f;
    float sd = 0.f;
    __syncthreads();

    // ---- phase 1: local chunk state ----
    for (int t = 0; t < CL; t++) {
        const float* row = ds + t * 48;
        float4 t0 = *(const float4*)(row + 0);
        float4 t1 = *(const float4*)(row + 4);
        float4 t2 = *(const float4*)(row + 8);
        float4 t3 = *(const float4*)(row + 12);
        float s = bdt;
        s += t0.x * wd[0].x + t0.y * wd[0].y + t0.z * wd[0].z + t0.w * wd[0].w;
        s += t1.x * wd[1].x + t1.y * wd[1].y + t1.z * wd[1].z + t1.w * wd[1].w;
        s += t2.x * wd[2].x + t2.y * wd[2].y + t2.z * wd[2].z + t2.w * wd[2].w;
        s += t3.x * wd[3].x + t3.y * wd[3].y + t3.z * wd[3].z + t3.w * wd[3].w;
        float dl = softplus_fast(s);
        long r = r0 + t;
        float u = bf2f(xmh[r * 512 + d]) + bf2f(xml[r * 512 + d]);
        uu[t] = u;
        float du = dl * u;
        sd += dl;
#pragma unroll
        for (int q = 0; q < 4; q++) {
            float4 bv = *(const float4*)(row + 16 + q * 4);
            float a0 = __expf(dl * Arow[q*4+0]); S[q*4+0] = a0 * S[q*4+0] + du * bv.x;
            float a1 = __expf(dl * Arow[q*4+1]); S[q*4+1] = a1 * S[q*4+1] + du * bv.y;
            float a2 = __expf(dl * Arow[q*4+2]); S[q*4+2] = a2 * S[q*4+2] + du * bv.z;
            float a3 = __expf(dl * Arow[q*4+3]); S[q*4+3] = a3 * S[q*4+3] + du * bv.w;
        }
    }
    long basei = ((long)(b * NC + c) * 16) * 512 + d;
#pragma unroll
    for (int n = 0; n < 16; n++) chunkS[basei + (long)n * 512] = S[n];
    sumdelta[(long)(b * NC + c) * 512 + d] = sd;

    __threadfence();
    grid.sync();

    // ---- combine: first 128 flat blocks handle 65536 (b,n,d) tasks ----
    int bid = blockIdx.y * 8 + blockIdx.x;   // 0..511
    if (bid < 128) {
        int idx = bid * 512 + d;
        int dd = idx & 511;
        int nn = (idx >> 9) & 15;
        int bb = idx >> 13;
        float Aval = -expf(A_log[dd * 16 + nn]);
        float h = 0.f;
        for (int cc = 0; cc < NC; cc++) {
            long si = ((long)(bb * NC + cc) * 16 + nn) * 512 + dd;
            float s = chunkS[si];
            float a = __expf(Aval * sumdelta[(long)(bb * NC + cc) * 512 + dd]);
            chunkS[si] = h;            // entry state for chunk cc
            h = a * h + s;
        }
    }

    __threadfence();
    grid.sync();

    // ---- phase 2: replay from entry state, emit y ----
    float Dd = Dv[d];
    float h[16];
#pragma unroll
    for (int n = 0; n < 16; n++) h[n] = chunkS[basei + (long)n * 512];

    for (int t = 0; t < CL; t++) {
        const float* row = ds + t * 48;
        float4 t0 = *(const float4*)(row + 0);
        float4 t1 = *(const float4*)(row + 4);
        float4 t2 = *(const float4*)(row + 8);
        float4 t3 = *(const float4*)(row + 12);
        float s = bdt;
        s += t0.x * wd[0].x + t0.y * wd[0].y + t0.z * wd[0].z + t0.w * wd[0].w;
        s += t1.x * wd[1].x + t1.y * wd[1].y + t1.z * wd[1].z + t1.w * wd[1].w;
        s += t2.x * wd[2].x + t2.y * wd[2].y + t2.z * wd[2].z + t2.w * wd[2].w;
        s += t3.x * wd[3].x + t3.y * wd[3].y + t3.z * wd[3].z + t3.w * wd[3].w;
        float dl = softplus_fast(s);
        long r = r0 + t;
        float u = uu[t];
        float res = xz[r * 1024 + 512 + d];
        float du = dl * u;
        float ysum = 0.f;
#pragma unroll
        for (int q = 0; q < 4; q++) {
            float4 bv = *(const float4*)(row + 16 + q * 4);
            float4 cv = *(const float4*)(row + 32 + q * 4);
            float a0 = __expf(dl * Arow[q*4+0]); h[q*4+0] = a0 * h[q*4+0] + du * bv.x; ysum += h[q*4+0] * cv.x;
            float a1 = __expf(dl * Arow[q*4+1]); h[q*4+1] = a1 * h[q*4+1] + du * bv.y; ysum += h[q*4+1] * cv.y;
            float a2 = __expf(dl * Arow[q*4+2]); h[q*4+2] = a2 * h[q*4+2] + du * bv.z; ysum += h[q*4+2] * cv.z;
            float a3 = __expf(dl * Arow[q*4+3]); h[q*4+3] = a3 * h[q*4+3] + du * bv.w; ysum += h[q*4+3] * cv.w;
        }
        float yy = ysum + u * Dd;
        float sres = res / (1.f + __expf(-res));
        float outv = yy * sres;
        u16 hh, ll;
        split2(outv, hh, ll);
        yh[r * 512 + d] = hh;
        yl[r * 512 + d] = ll;
    }
}

// ---------------------------------------------------------------------------
// head: reduce 16 block partials per batch -> pooled, classify
// ---------------------------------------------------------------------------
__global__ __launch_bounds__(256) void head_kernel(const float* __restrict__ bp,
                                                   const float* __restrict__ fw,
                                                   const float* __restrict__ fb,
                                                   float* __restrict__ out) {
    __shared__ float pld[256];
    int b = blockIdx.x;
    int d = threadIdx.x;
    float s = 0.f;
#pragma unroll
    for (int i = 0; i < 16; i++)
        s += bp[(long)(b * 16 + i) * 256 + d];
    pld[d] = s;
    __syncthreads();
    if (d < N_CLASSES) {
        float acc = 0.f;
        for (int k = 0; k < 256; k++) acc += pld[k] * fw[d * 256 + k];
        out[b * N_CLASSES + d] = acc * (1.f / (float)Tt) + fb[d];
    }
}

// ---------------------------------------------------------------------------
extern "C" void kernel_launch(void* const* d_in, const int* in_sizes, int n_in,
                              void* d_out, int out_size, void* d_ws, size_t ws_size,
                              hipStream_t stream) {
    const float* x         = (const float*)d_in[0];
    const float* embed_w   = (const float*)d_in[1];
    const float* embed_b   = (const float*)d_in[2];
    const float* pre_g     = (const float*)d_in[3];
    const float* pre_b     = (const float*)d_in[4];
    const float* in_proj_w = (const float*)d_in[5];
    const float* conv_w    = (const float*)d_in[6];
    const float* conv_b    = (const float*)d_in[7];
    const float* x_proj_w  = (const float*)d_in[8];
    const float* dt_proj_w = (const float*)d_in[9];
    const float* dt_proj_b = (const float*)d_in[10];
    const float* A_log     = (const float*)d_in[11];
    const float* Dv        = (const float*)d_in[12];
    const float* out_proj_w= (const float*)d_in[13];
    const float* post_g    = (const float*)d_in[14];
    const float* post_b    = (const float*)d_in[15];
    const float* fine_w    = (const float*)d_in[16];
    const float* fine_b    = (const float*)d_in[17];
    float* out = (float*)d_out;
    char* base = (char*)d_ws;

    // workspace layout (bytes) — total ~88.6 MB
    float* feat     = (float*)(base + 0);          //  8 MB fp32 [M,256]
    float* xz       = (float*)(base + 8388608);    // 32 MB fp32 [M,1024]
    float* chunkS   = (float*)(base + 41943040);   // 16 MB [8*NC,16,512]
    u16*   xmh      = (u16*)  (base + 58720256);   //  8 MB bf16 [M,512] (-> y hi)
    u16*   xml      = (u16*)  (base + 67108864);   //  8 MB bf16 [M,512] (-> y lo)
    u16*   fbh      = (u16*)  (base + 75497472);   //  4 MB featbf hi -> hn hi
    u16*   fbl      = (u16*)  (base + 79691776);   //  4 MB featbf lo -> hn lo
    float* dbl      = (float*)(base + 83886080);   //  1.5 MB fp32 [M,48]
    float* sumdelta = (float*)(base + 85458944);   //  1 MB
    float* blockpart= (float*)(base + 86507520);   //  128 KB [128][256]
    u16*   ebh      = (u16*)  (base + 86638592);   // weight bf16 buffers (~1.9 MB)
    u16*   ebl      = ebh + 65536;
    u16*   iph      = ebl + 65536;
    u16*   ipl      = iph + 262144;
    u16*   xph      = ipl + 262144;
    u16*   xpl      = xph + 24576;
    u16*   oph      = xpl + 24576;
    u16*   opl      = oph + 131072;

    // 1. featurize + weight conversion + blockpart zeroing (one dispatch)
    prep_kernel<<<dim3(Mrows + 1888 + 128), dim3(256), 0, stream>>>(
        x, fbh, fbl, embed_w, in_proj_w, x_proj_w, out_proj_w,
        ebh, ebl, iph, ipl, xph, xpl, oph, opl, blockpart);

    // 2. embed GEMM + bias -> feat fp32  (<64,64> grid 4x128 = 512 blocks, 2/CU)
    gemm_mfma<64,64,1><<<dim3(4, 128), dim3(256), 0, stream>>>(
        fbh, fbl, 256, ebh, ebl, 256, embed_b, nullptr, 0, feat, 256, Mrows, 256, 256);

    // 3. pre-LN -> hn bf16 hi/lo (in-place over featbf; 8192 blocks)
    ln_kernel<<<dim3(Mrows), dim3(256), 0, stream>>>(feat, pre_g, pre_b, fbh, fbl);

    // 4. in_proj: xz = hn @ ipw^T  (<128,64> grid 16x64 = 1024 blocks, 4/CU)
    gemm_mfma<128,64,0><<<dim3(16, 64), dim3(256), 0, stream>>>(
        fbh, fbl, 256, iph, ipl, 256, nullptr, nullptr, 0, xz, 1024, Mrows, 1024, 256);

    // 5. fused conv+silu+x_proj -> xm bf16 + dbl  (BM=16, 512 blocks, 2/CU)
    conv_xproj_kernel<<<dim3(Mrows / 16), dim3(256), 0, stream>>>(
        xz, conv_w, conv_b, xph, xpl, xmh, xml, dbl);

    // 6. fused cooperative scan (p1 + combine + p2); writes y bf16 over xm
    {
        void* args[] = {
            (void*)&dbl, (void*)&dt_proj_w, (void*)&dt_proj_b,
            (void*)&xmh, (void*)&xml, (void*)&xz,
            (void*)&A_log, (void*)&Dv,
            (void*)&chunkS, (void*)&sumdelta,
            (void*)&xmh, (void*)&xml
        };
        hipLaunchCooperativeKernel((void*)scan_fused, dim3(Bb, NC), dim3(512),
                                   args, 0, stream);
    }

    // 7. out_proj + residual -> feat (in-place)  (<64,64> grid 4x128 = 512, 2/CU)
    gemm_mfma<64,64,3><<<dim3(4, 128), dim3(256), 0, stream>>>(
        xmh, xml, 512, oph, opl, 512, nullptr, feat, 256, feat, 256, Mrows, 256, 512);

    // 8. post-LN + pool partials (8192 blocks, atomic into pre-zeroed blockpart)
    ln_pool_kernel<<<dim3(Mrows), dim3(256), 0, stream>>>(feat, post_g, post_b, blockpart);

    // 9. head
    head_kernel<<<dim3(Bb), dim3(256), 0, stream>>>(blockpart, fine_w, fine_b, out);
}

// Round 11
// 258.344 us; speedup vs baseline: 2.3102x; 2.3102x over previous
//
#include <hip/hip_runtime.h>
#include <hip/hip_bf16.h>
#include <math.h>

// Problem constants
#define Bb 8
#define Tt 1024
#define Jj 25
#define D_MODEL 256
#define D_STATE 16
#define D_CONV 4
#define D_INNER 512
#define DT_RANK 16
#define N_CLASSES 60
#define Mrows (Bb*Tt)   // 8192
#define NC 64           // scan chunks
#define CL 16           // chunk length (NC*CL == Tt)

typedef unsigned short u16;
using bf16x8 = __attribute__((ext_vector_type(8))) __bf16;
using f32x4  = __attribute__((ext_vector_type(4))) float;

// ---- bf16 split helpers ----------------------------------------------------
__device__ inline u16 f2bf(float x) {
    unsigned u = __float_as_uint(x);
    unsigned r = (u + 0x7fffu + ((u >> 16) & 1u)) >> 16;
    return (u16)r;
}
__device__ inline float bf2f(u16 h) { return __uint_as_float((unsigned)h << 16); }
__device__ inline void split2(float x, u16& h, u16& l) {
    h = f2bf(x);
    l = f2bf(x - bf2f(h));
}
__device__ inline float softplus_fast(float s) {
    return fmaxf(s, 0.f) + __logf(1.f + __expf(-fabsf(s)));
}
__device__ inline f32x4 mfma3(bf16x8 ah, bf16x8 al, bf16x8 bh, bf16x8 bl, f32x4 c) {
    c = __builtin_amdgcn_mfma_f32_16x16x32_bf16(al, bh, c, 0, 0, 0);
    c = __builtin_amdgcn_mfma_f32_16x16x32_bf16(ah, bl, c, 0, 0, 0);
    c = __builtin_amdgcn_mfma_f32_16x16x32_bf16(ah, bh, c, 0, 0, 0);
    return c;
}

// ---------------------------------------------------------------------------
// prep: blocks 0..8191 featurize; 8192..10079 weight cvt; 10080..10207 zero bp
// ---------------------------------------------------------------------------
__global__ __launch_bounds__(256) void prep_kernel(
    const float* __restrict__ x, u16* __restrict__ fh, u16* __restrict__ fl,
    const float* __restrict__ ew, const float* __restrict__ iw,
    const float* __restrict__ xw, const float* __restrict__ ow,
    u16* __restrict__ ebh, u16* __restrict__ ebl,
    u16* __restrict__ iph, u16* __restrict__ ipl,
    u16* __restrict__ xph, u16* __restrict__ xpl,
    u16* __restrict__ oph, u16* __restrict__ opl,
    float* __restrict__ blockpart) {
    int blk = blockIdx.x;
    if (blk < Mrows) {
        int r = blk;
        int c = threadIdx.x;
        float v = 0.f;
        if (c < 225) {
            int t = r & (Tt - 1);
            int j = c / 9;
            int cc = c - j * 9;
            int comp = cc % 3;
            int kind = cc / 3;
            auto POS = [&](int dt) -> float {
                const float* p = x + (long)(r - dt) * Jj * 3;
                return p[j * 3 + comp] - p[comp];
            };
            if (kind == 0) v = POS(0);
            else if (kind == 1) v = (t >= 1) ? (POS(0) - POS(1)) : 0.f;
            else {
                if (t >= 2)      v = POS(0) - 2.f * POS(1) + POS(2);
                else if (t == 1) v = POS(0) - POS(1);
                else             v = 0.f;
            }
        }
        u16 h, l;
        split2(v, h, l);
        fh[(long)r * 256 + c] = h;
        fl[(long)r * 256 + c] = l;
    } else if (blk < Mrows + 1888) {
        int i = (blk - Mrows) * 256 + threadIdx.x;   // 0..483327
        const float* src; u16 *dh, *dl; int K, kshift, idx;
        if (i < 65536)       { src = ew; dh = ebh; dl = ebl; K = 225; kshift = 8; idx = i; }
        else if (i < 327680) { src = iw; dh = iph; dl = ipl; K = 256; kshift = 8; idx = i - 65536; }
        else if (i < 352256) { src = xw; dh = xph; dl = xpl; K = 512; kshift = 9; idx = i - 327680; }
        else                 { src = ow; dh = oph; dl = opl; K = 512; kshift = 9; idx = i - 352256; }
        int n = idx >> kshift;
        int k = idx & ((1 << kshift) - 1);
        float v = (k < K) ? src[(long)n * K + k] : 0.f;
        u16 h, l;
        split2(v, h, l);
        dh[idx] = h;
        dl[idx] = l;
    } else {
        int i = (blk - Mrows - 1888) * 256 + threadIdx.x;
        blockpart[i] = 0.f;
    }
}

// ---------------------------------------------------------------------------
// bf16x3 MFMA GEMM with epilogue. EPI: 0=none, 1=+bias, 3=+resid
// Shapes for >=2 co-resident blocks/CU:
//   <64,64>: LDS 20.5 KB, grid 512 -> 2/CU.  <128,64>: LDS 30.7 KB, grid 1024 -> 4/CU.
// ---------------------------------------------------------------------------
template<int BM, int BN, int EPI>
__global__ __launch_bounds__(256) void gemm_mfma(
    const u16* __restrict__ Ahi, const u16* __restrict__ Alo, int lda,
    const u16* __restrict__ Whi, const u16* __restrict__ Wlo, int ldw,
    const float* __restrict__ bias, const float* __restrict__ resid, int ldr,
    float* __restrict__ C, int ldc, int M, int N, int K)
{
    constexpr int TM = BM / 32;
    constexpr int TN = BN / 32;
    constexpr int SA = 40;
    __shared__ u16 AsH[BM * SA], AsL[BM * SA];
    __shared__ u16 WsH[BN * SA], WsL[BN * SA];
    int tid = threadIdx.x;
    int m0 = blockIdx.y * BM;
    int n0 = blockIdx.x * BN;
    int lane = tid & 63;
    int wave = tid >> 6;
    int wm = wave >> 1, wn = wave & 1;
    int fr = lane & 15, quad = lane >> 4;
    f32x4 acc[TM][TN] = {};

    for (int k0 = 0; k0 < K; k0 += 32) {
        for (int s = tid; s < BM * 4; s += 256) {
            int row = s >> 2, seg = s & 3;
            long off = (long)(m0 + row) * lda + k0 + seg * 8;
            *(uint4*)&AsH[row * SA + seg * 8] = *(const uint4*)(Ahi + off);
            *(uint4*)&AsL[row * SA + seg * 8] = *(const uint4*)(Alo + off);
        }
        for (int s = tid; s < BN * 4; s += 256) {
            int row = s >> 2, seg = s & 3;
            long off = (long)(n0 + row) * ldw + k0 + seg * 8;
            *(uint4*)&WsH[row * SA + seg * 8] = *(const uint4*)(Whi + off);
            *(uint4*)&WsL[row * SA + seg * 8] = *(const uint4*)(Wlo + off);
        }
        __syncthreads();
        bf16x8 aH[TM], aL[TM], bH[TN], bL[TN];
#pragma unroll
        for (int im = 0; im < TM; im++) {
            int r = wm * (BM / 2) + im * 16 + fr;
            aH[im] = *(const bf16x8*)&AsH[r * SA + quad * 8];
            aL[im] = *(const bf16x8*)&AsL[r * SA + quad * 8];
        }
#pragma unroll
        for (int in = 0; in < TN; in++) {
            int r = wn * (BN / 2) + in * 16 + fr;
            bH[in] = *(const bf16x8*)&WsH[r * SA + quad * 8];
            bL[in] = *(const bf16x8*)&WsL[r * SA + quad * 8];
        }
#pragma unroll
        for (int im = 0; im < TM; im++)
#pragma unroll
            for (int in = 0; in < TN; in++)
                acc[im][in] = mfma3(aH[im], aL[im], bH[in], bL[in], acc[im][in]);
        __syncthreads();
    }
#pragma unroll
    for (int im = 0; im < TM; im++) {
#pragma unroll
        for (int in = 0; in < TN; in++) {
#pragma unroll
            for (int reg = 0; reg < 4; reg++) {
                int gm = m0 + wm * (BM / 2) + im * 16 + quad * 4 + reg;
                int gn = n0 + wn * (BN / 2) + in * 16 + fr;
                float v = acc[im][in][reg];
                if (EPI == 1) v += bias[gn];
                if (EPI == 3) v += resid[(long)gm * ldr + gn];
                C[(long)gm * ldc + gn] = v;
            }
        }
    }
}

// ---------------------------------------------------------------------------
// LayerNorm over D=256 per row (8192 blocks) -> bf16 hi/lo.
// ---------------------------------------------------------------------------
__global__ __launch_bounds__(256) void ln_kernel(const float* __restrict__ x,
                                                 const float* __restrict__ g,
                                                 const float* __restrict__ b,
                                                 u16* outh, u16* outl) {
    __shared__ float red[256];
    long r = blockIdx.x;
    int d = threadIdx.x;
    float v = x[r * 256 + d];
    red[d] = v;
    __syncthreads();
    for (int s = 128; s > 0; s >>= 1) {
        if (d < s) red[d] += red[d + s];
        __syncthreads();
    }
    float mu = red[0] * (1.f / 256.f);
    __syncthreads();
    float dv = v - mu;
    red[d] = dv * dv;
    __syncthreads();
    for (int s = 128; s > 0; s >>= 1) {
        if (d < s) red[d] += red[d + s];
        __syncthreads();
    }
    float var = red[0] * (1.f / 256.f);
    float o = dv * rsqrtf(var + 1e-5f) * g[d] + b[d];
    u16 h, l;
    split2(o, h, l);
    outh[r * 256 + d] = h;
    outl[r * 256 + d] = l;
}

// ---------------------------------------------------------------------------
// Post-LN + pool partial: per-row LN, atomicAdd into blockpart[r/64][d].
// ---------------------------------------------------------------------------
__global__ __launch_bounds__(256) void ln_pool_kernel(const float* __restrict__ x,
                                                      const float* __restrict__ g,
                                                      const float* __restrict__ b,
                                                      float* __restrict__ bp) {
    __shared__ float red[256];
    long r = blockIdx.x;
    int d = threadIdx.x;
    float v = x[r * 256 + d];
    red[d] = v;
    __syncthreads();
    for (int s = 128; s > 0; s >>= 1) {
        if (d < s) red[d] += red[d + s];
        __syncthreads();
    }
    float mu = red[0] * (1.f / 256.f);
    __syncthreads();
    float dv = v - mu;
    red[d] = dv * dv;
    __syncthreads();
    for (int s = 128; s > 0; s >>= 1) {
        if (d < s) red[d] += red[d + s];
        __syncthreads();
    }
    float var = red[0] * (1.f / 256.f);
    float o = dv * rsqrtf(var + 1e-5f) * g[d] + b[d];
    atomicAdd(&bp[(r >> 6) * 256 + d], o);
}

// ---------------------------------------------------------------------------
// Fused conv+SiLU+x_proj. BM=16 rows/block, grid 512 -> 2 blocks/CU.
// ---------------------------------------------------------------------------
__global__ __launch_bounds__(256) void conv_xproj_kernel(
    const float* __restrict__ xz,
    const float* __restrict__ cw, const float* __restrict__ cb,
    const u16* __restrict__ Whi, const u16* __restrict__ Wlo,  // [48][512]
    u16* __restrict__ xmh, u16* __restrict__ xml,
    float* __restrict__ dbl)
{
    constexpr int SA = 40;
    __shared__ u16 AsH[16 * SA], AsL[16 * SA];
    __shared__ u16 WsH[64 * SA], WsL[64 * SA];
    int tid = threadIdx.x;
    int m0 = blockIdx.x * 16;
    int lane = tid & 63, wave = tid >> 6;
    int fr = lane & 15, quad = lane >> 4;
    f32x4 acc = {};

    if (tid < 64) {
        int wr = 48 + (tid >> 2), seg = tid & 3;
        *(uint4*)&WsH[wr * SA + seg * 8] = make_uint4(0, 0, 0, 0);
        *(uint4*)&WsL[wr * SA + seg * 8] = make_uint4(0, 0, 0, 0);
    }

    int row = tid >> 4;          // 0..15
    int cg  = tid & 15;          // 2 cols each
    long gr = m0 + row;
    int t = gr & (Tt - 1);
    const float* xzr = xz + gr * 1024;

    for (int k0 = 0; k0 < 512; k0 += 32) {
        int c0 = k0 + cg * 2;
        float2 x0 = *(const float2*)(xzr + c0);
        float2 x1 = (t >= 1) ? *(const float2*)(xzr - 1024 + c0) : make_float2(0, 0);
        float2 x2 = (t >= 2) ? *(const float2*)(xzr - 2048 + c0) : make_float2(0, 0);
        float2 x3 = (t >= 3) ? *(const float2*)(xzr - 3072 + c0) : make_float2(0, 0);
        u16 hh0, ll0, hh1, ll1;
        {
            float4 w = *(const float4*)(cw + (c0 + 0) * 4);
            float a = cb[c0 + 0] + w.w * x0.x + w.z * x1.x + w.y * x2.x + w.x * x3.x;
            float s = a / (1.f + __expf(-a));
            split2(s, hh0, ll0);
            w = *(const float4*)(cw + (c0 + 1) * 4);
            a = cb[c0 + 1] + w.w * x0.y + w.z * x1.y + w.y * x2.y + w.x * x3.y;
            s = a / (1.f + __expf(-a));
            split2(s, hh1, ll1);
        }
        unsigned ph = hh0 | ((unsigned)hh1 << 16);
        unsigned pl = ll0 | ((unsigned)ll1 << 16);
        *(unsigned*)(xmh + gr * 512 + c0) = ph;
        *(unsigned*)(xml + gr * 512 + c0) = pl;
        *(unsigned*)&AsH[row * SA + cg * 2] = ph;
        *(unsigned*)&AsL[row * SA + cg * 2] = pl;
        if (tid < 192) {
            int wr = tid >> 2, seg = tid & 3;
            long off = (long)wr * 512 + k0 + seg * 8;
            *(uint4*)&WsH[wr * SA + seg * 8] = *(const uint4*)(Whi + off);
            *(uint4*)&WsL[wr * SA + seg * 8] = *(const uint4*)(Wlo + off);
        }
        __syncthreads();
        bf16x8 aH = *(const bf16x8*)&AsH[fr * SA + quad * 8];
        bf16x8 aL = *(const bf16x8*)&AsL[fr * SA + quad * 8];
        int wrow = wave * 16 + fr;
        bf16x8 bH = *(const bf16x8*)&WsH[wrow * SA + quad * 8];
        bf16x8 bL = *(const bf16x8*)&WsL[wrow * SA + quad * 8];
        acc = mfma3(aH, aL, bH, bL, acc);
        __syncthreads();
    }
    int gn = wave * 16 + fr;
    if (gn < 48) {
#pragma unroll
        for (int reg = 0; reg < 4; reg++) {
            int gm = m0 + quad * 4 + reg;
            dbl[(long)gm * 48 + gn] = acc[reg];
        }
    }
}

// ---------------------------------------------------------------------------
// Chunked selective scan, 512-thread blocks, LDS-staged dbl slab, fused dt_proj.
// ---------------------------------------------------------------------------
__global__ __launch_bounds__(512) void scan_p1(const float* __restrict__ dbl,
                                               const float* __restrict__ dtw,
                                               const float* __restrict__ dtb,
                                               const u16* __restrict__ xmh,
                                               const u16* __restrict__ xml,
                                               const float* __restrict__ A_log,
                                               float* __restrict__ chunkS,
                                               float* __restrict__ sumdelta) {
    __shared__ float ds[CL * 48];
    int b = blockIdx.x, c = blockIdx.y, d = threadIdx.x;
    long r0 = (long)b * Tt + (long)c * CL;
    for (int i = d; i < CL * 48; i += 512) ds[i] = dbl[r0 * 48 + i];

    float Arow[16];
#pragma unroll
    for (int n = 0; n < 16; n++) Arow[n] = -expf(A_log[d * 16 + n]);
    float4 wd[4];
#pragma unroll
    for (int q = 0; q < 4; q++) wd[q] = *(const float4*)(dtw + d * 16 + q * 4);
    float bdt = dtb[d];
    float S[16];
#pragma unroll
    for (int n = 0; n < 16; n++) S[n] = 0.f;
    float sd = 0.f;
    __syncthreads();

    for (int t = 0; t < CL; t++) {
        const float* row = ds + t * 48;
        float4 t0 = *(const float4*)(row + 0);
        float4 t1 = *(const float4*)(row + 4);
        float4 t2 = *(const float4*)(row + 8);
        float4 t3 = *(const float4*)(row + 12);
        float s = bdt;
        s += t0.x * wd[0].x + t0.y * wd[0].y + t0.z * wd[0].z + t0.w * wd[0].w;
        s += t1.x * wd[1].x + t1.y * wd[1].y + t1.z * wd[1].z + t1.w * wd[1].w;
        s += t2.x * wd[2].x + t2.y * wd[2].y + t2.z * wd[2].z + t2.w * wd[2].w;
        s += t3.x * wd[3].x + t3.y * wd[3].y + t3.z * wd[3].z + t3.w * wd[3].w;
        float dl = softplus_fast(s);
        long r = r0 + t;
        float u = bf2f(xmh[r * 512 + d]) + bf2f(xml[r * 512 + d]);
        float du = dl * u;
        sd += dl;
        float Bn[16];
#pragma unroll
        for (int q = 0; q < 4; q++) {
            float4 bv = *(const float4*)(row + 16 + q * 4);
            Bn[q*4+0] = bv.x; Bn[q*4+1] = bv.y; Bn[q*4+2] = bv.z; Bn[q*4+3] = bv.w;
        }
#pragma unroll
        for (int n = 0; n < 16; n++) {
            float a = __expf(dl * Arow[n]);
            S[n] = a * S[n] + du * Bn[n];
        }
    }
    long base = ((long)(b * NC + c) * 16) * 512 + d;
#pragma unroll
    for (int n = 0; n < 16; n++) chunkS[base + (long)n * 512] = S[n];
    sumdelta[(long)(b * NC + c) * 512 + d] = sd;
}

__global__ __launch_bounds__(256) void scan_combine(float* chunkS,
                                                    const float* __restrict__ sumdelta,
                                                    const float* __restrict__ A_log) {
    int idx = blockIdx.x * 256 + threadIdx.x;
    int d = idx & 511;
    int n = (idx >> 9) & 15;
    int b = idx >> 13;
    float Aval = -expf(A_log[d * 16 + n]);
    float h = 0.f;
    for (int c = 0; c < NC; c++) {
        long si = ((long)(b * NC + c) * 16 + n) * 512 + d;
        float s = chunkS[si];
        float a = __expf(Aval * sumdelta[(long)(b * NC + c) * 512 + d]);
        chunkS[si] = h;
        h = a * h + s;
    }
}

__global__ __launch_bounds__(512) void scan_p2(const float* __restrict__ dbl,
                                               const float* __restrict__ dtw,
                                               const float* __restrict__ dtb,
                                               const u16* xmh, const u16* xml,
                                               const float* __restrict__ xz,
                                               const float* __restrict__ A_log,
                                               const float* __restrict__ Dv,
                                               const float* __restrict__ chunkH,
                                               u16* yh, u16* yl) {
    __shared__ float ds[CL * 48];
    int b = blockIdx.x, c = blockIdx.y, d = threadIdx.x;
    long r0 = (long)b * Tt + (long)c * CL;
    for (int i = d; i < CL * 48; i += 512) ds[i] = dbl[r0 * 48 + i];

    float Arow[16];
#pragma unroll
    for (int n = 0; n < 16; n++) Arow[n] = -expf(A_log[d * 16 + n]);
    float4 wd[4];
#pragma unroll
    for (int q = 0; q < 4; q++) wd[q] = *(const float4*)(dtw + d * 16 + q * 4);
    float bdt = dtb[d];
    float Dd = Dv[d];
    float h[16];
    long base = ((long)(b * NC + c) * 16) * 512 + d;
#pragma unroll
    for (int n = 0; n < 16; n++) h[n] = chunkH[base + (long)n * 512];
    __syncthreads();

    for (int t = 0; t < CL; t++) {
        const float* row = ds + t * 48;
        float4 t0 = *(const float4*)(row + 0);
        float4 t1 = *(const float4*)(row + 4);
        float4 t2 = *(const float4*)(row + 8);
        float4 t3 = *(const float4*)(row + 12);
        float s = bdt;
        s += t0.x * wd[0].x + t0.y * wd[0].y + t0.z * wd[0].z + t0.w * wd[0].w;
        s += t1.x * wd[1].x + t1.y * wd[1].y + t1.z * wd[1].z + t1.w * wd[1].w;
        s += t2.x * wd[2].x + t2.y * wd[2].y + t2.z * wd[2].z + t2.w * wd[2].w;
        s += t3.x * wd[3].x + t3.y * wd[3].y + t3.z * wd[3].z + t3.w * wd[3].w;
        float dl = softplus_fast(s);
        long r = r0 + t;
        float u = bf2f(xmh[r * 512 + d]) + bf2f(xml[r * 512 + d]);
        float res = xz[r * 1024 + 512 + d];
        float du = dl * u;
        float Bn[16], Cn[16];
#pragma unroll
        for (int q = 0; q < 4; q++) {
            float4 bv = *(const float4*)(row + 16 + q * 4);
            float4 cv = *(const float4*)(row + 32 + q * 4);
            Bn[q*4+0] = bv.x; Bn[q*4+1] = bv.y; Bn[q*4+2] = bv.z; Bn[q*4+3] = bv.w;
            Cn[q*4+0] = cv.x; Cn[q*4+1] = cv.y; Cn[q*4+2] = cv.z; Cn[q*4+3] = cv.w;
        }
        float ysum = 0.f;
#pragma unroll
        for (int n = 0; n < 16; n++) {
            float a = __expf(dl * Arow[n]);
            h[n] = a * h[n] + du * Bn[n];
            ysum += h[n] * Cn[n];
        }
        float yy = ysum + u * Dd;
        float sres = res / (1.f + __expf(-res));
        float outv = yy * sres;
        u16 hh, ll;
        split2(outv, hh, ll);
        yh[r * 512 + d] = hh;
        yl[r * 512 + d] = ll;
    }
}

// ---------------------------------------------------------------------------
// head: reduce 16 block partials per batch -> pooled, classify
// ---------------------------------------------------------------------------
__global__ __launch_bounds__(256) void head_kernel(const float* __restrict__ bp,
                                                   const float* __restrict__ fw,
                                                   const float* __restrict__ fb,
                                                   float* __restrict__ out) {
    __shared__ float pld[256];
    int b = blockIdx.x;
    int d = threadIdx.x;
    float s = 0.f;
#pragma unroll
    for (int i = 0; i < 16; i++)
        s += bp[(long)(b * 16 + i) * 256 + d];
    pld[d] = s;
    __syncthreads();
    if (d < N_CLASSES) {
        float acc = 0.f;
        for (int k = 0; k < 256; k++) acc += pld[k] * fw[d * 256 + k];
        out[b * N_CLASSES + d] = acc * (1.f / (float)Tt) + fb[d];
    }
}

// ---------------------------------------------------------------------------
extern "C" void kernel_launch(void* const* d_in, const int* in_sizes, int n_in,
                              void* d_out, int out_size, void* d_ws, size_t ws_size,
                              hipStream_t stream) {
    const float* x         = (const float*)d_in[0];
    const float* embed_w   = (const float*)d_in[1];
    const float* embed_b   = (const float*)d_in[2];
    const float* pre_g     = (const float*)d_in[3];
    const float* pre_b     = (const float*)d_in[4];
    const float* in_proj_w = (const float*)d_in[5];
    const float* conv_w    = (const float*)d_in[6];
    const float* conv_b    = (const float*)d_in[7];
    const float* x_proj_w  = (const float*)d_in[8];
    const float* dt_proj_w = (const float*)d_in[9];
    const float* dt_proj_b = (const float*)d_in[10];
    const float* A_log     = (const float*)d_in[11];
    const float* Dv        = (const float*)d_in[12];
    const float* out_proj_w= (const float*)d_in[13];
    const float* post_g    = (const float*)d_in[14];
    const float* post_b    = (const float*)d_in[15];
    const float* fine_w    = (const float*)d_in[16];
    const float* fine_b    = (const float*)d_in[17];
    float* out = (float*)d_out;
    char* base = (char*)d_ws;

    // workspace layout (bytes) — total ~88.6 MB
    float* feat     = (float*)(base + 0);          //  8 MB fp32 [M,256]
    float* xz       = (float*)(base + 8388608);    // 32 MB fp32 [M,1024]
    float* chunkS   = (float*)(base + 41943040);   // 16 MB [8*NC,16,512]
    u16*   xmh      = (u16*)  (base + 58720256);   //  8 MB bf16 [M,512] (-> y hi)
    u16*   xml      = (u16*)  (base + 67108864);   //  8 MB bf16 [M,512] (-> y lo)
    u16*   fbh      = (u16*)  (base + 75497472);   //  4 MB featbf hi -> hn hi
    u16*   fbl      = (u16*)  (base + 79691776);   //  4 MB featbf lo -> hn lo
    float* dbl      = (float*)(base + 83886080);   //  1.5 MB fp32 [M,48]
    float* sumdelta = (float*)(base + 85458944);   //  1 MB
    float* blockpart= (float*)(base + 86507520);   //  128 KB [128][256]
    u16*   ebh      = (u16*)  (base + 86638592);   // weight bf16 buffers (~1.9 MB)
    u16*   ebl      = ebh + 65536;
    u16*   iph      = ebl + 65536;
    u16*   ipl      = iph + 262144;
    u16*   xph      = ipl + 262144;
    u16*   xpl      = xph + 24576;
    u16*   oph      = xpl + 24576;
    u16*   opl      = oph + 131072;

    // 1. featurize + weight conversion + blockpart zeroing (one dispatch)
    prep_kernel<<<dim3(Mrows + 1888 + 128), dim3(256), 0, stream>>>(
        x, fbh, fbl, embed_w, in_proj_w, x_proj_w, out_proj_w,
        ebh, ebl, iph, ipl, xph, xpl, oph, opl, blockpart);

    // 2. embed GEMM + bias -> feat fp32  (<64,64> grid 4x128 = 512 blocks, 2/CU)
    gemm_mfma<64,64,1><<<dim3(4, 128), dim3(256), 0, stream>>>(
        fbh, fbl, 256, ebh, ebl, 256, embed_b, nullptr, 0, feat, 256, Mrows, 256, 256);

    // 3. pre-LN -> hn bf16 hi/lo (in-place over featbf; 8192 blocks)
    ln_kernel<<<dim3(Mrows), dim3(256), 0, stream>>>(feat, pre_g, pre_b, fbh, fbl);

    // 4. in_proj: xz = hn @ ipw^T  (<128,64> grid 16x64 = 1024 blocks, 4/CU)
    gemm_mfma<128,64,0><<<dim3(16, 64), dim3(256), 0, stream>>>(
        fbh, fbl, 256, iph, ipl, 256, nullptr, nullptr, 0, xz, 1024, Mrows, 1024, 256);

    // 5. fused conv+silu+x_proj -> xm bf16 + dbl  (BM=16, 512 blocks, 2/CU)
    conv_xproj_kernel<<<dim3(Mrows / 16), dim3(256), 0, stream>>>(
        xz, conv_w, conv_b, xph, xpl, xmh, xml, dbl);

    // 6. chunked selective scan (dt_proj fused); p2 writes y bf16 over xm
    //    NOTE: 3 dispatches on purpose — cooperative grid.sync costs ~150 µs
    //    per sync on 8 non-coherent XCDs (R10 post-mortem); launch boundaries
    //    are far cheaper.
    scan_p1<<<dim3(Bb, NC), dim3(512), 0, stream>>>(
        dbl, dt_proj_w, dt_proj_b, xmh, xml, A_log, chunkS, sumdelta);
    scan_combine<<<dim3(256), dim3(256), 0, stream>>>(chunkS, sumdelta, A_log);
    scan_p2<<<dim3(Bb, NC), dim3(512), 0, stream>>>(
        dbl, dt_proj_w, dt_proj_b, xmh, xml, xz, A_log, Dv, chunkS, xmh, xml);

    // 7. out_proj + residual -> feat (in-place)  (<64,64> grid 4x128 = 512, 2/CU)
    gemm_mfma<64,64,3><<<dim3(4, 128), dim3(256), 0, stream>>>(
        xmh, xml, 512, oph, opl, 512, nullptr, feat, 256, feat, 256, Mrows, 256, 512);

    // 8. post-LN + pool partials (8192 blocks, atomic into pre-zeroed blockpart)
    ln_pool_kernel<<<dim3(Mrows), dim3(256), 0, stream>>>(feat, post_g, post_b, blockpart);

    // 9. head
    head_kernel<<<dim3(Bb), dim3(256), 0, stream>>>(blockpart, fine_w, fine_b, out);
}